// Round 1
// 550.872 us; speedup vs baseline: 1.2982x; 1.2982x over previous
//
#include <hip/hip_runtime.h>
#include <hip/hip_bf16.h>

typedef __attribute__((ext_vector_type(8))) short short8;
typedef __attribute__((ext_vector_type(4))) float f32x4;

#define NTOP 1000
#define NPAD 1024
#define KC   256
#define MROWS 40000

static __device__ __forceinline__ unsigned short f2bf(float x) {
    union { float f; unsigned u; } v; v.f = x;
    unsigned r = (v.u + 0x7FFFu + ((v.u >> 16) & 1u)) >> 16;
    return (unsigned short)r;
}

// Kernel 1: colsum[j] += sum over an 8-row slab of nw. colsum pre-zeroed by memset.
__global__ void k_prep(const float* __restrict__ nw,
                       float* __restrict__ colsum) {
    int j  = blockIdx.x * 256 + threadIdx.x;
    int i0 = blockIdx.y * 8;
    if (j < NTOP) {
        float s = 0.f;
        int iend = min(i0 + 8, NTOP);
        for (int i = i0; i < iend; ++i) s += nw[(size_t)i * NTOP + j];
        atomicAdd(colsum + j, s);
    }
}

// Kernel 2: build B' in MFMA-fragment order:
//   B'[((nt*8 + s)*64 + lane)] (short8) = V_j[n = nt*16 + (lane&15),
//                                             k = s*32 + (lane>>4)*8 + j]
// so k_main's B-fragment load is ONE contiguous coalesced 1 KB segment.
__global__ void k_vj(const float* __restrict__ V,
                     const float* __restrict__ noise,
                     const float* __restrict__ colsum,
                     unsigned short* __restrict__ Bp) {
    int t  = blockIdx.x * 256 + threadIdx.x;   // 0 .. 64*8*64-1 = 32767
    int nt = t >> 9;
    int s  = (t >> 6) & 7;
    int l  = t & 63;
    int lm = l & 15, lq = l >> 4;
    int n  = nt * 16 + lm;
    int k0 = s * 32 + lq * 8;
    union { short8 v; unsigned short us[8]; } pk;
    if (n < NTOP) {
        float cs = colsum[n];
        #pragma unroll
        for (int j = 0; j < 8; ++j) {
            int idx = n * KC + k0 + j;
            pk.us[j] = f2bf(V[idx] * cs + 0.1f * noise[idx]);
        }
    } else {
        #pragma unroll
        for (int j = 0; j < 8; ++j) pk.us[j] = 0;
    }
    reinterpret_cast<short8*>(Bp)[t] = pk.v;
}

// Kernel 3: fused U_emb + GEMM + sigmoid + masked Normal log-prob + reduce.
// v2 changes vs previous best:
//  - U_emb tile (16 rows x 256 k) built COOPERATIVELY once per block into LDS
//    (was: rebuilt redundantly by each of the 4 waves) -> 4x fewer U loads.
//  - MFMA operands SWAPPED: acc = mfma(bfr, afr). A/B fragment layouts are
//    identical for 16x16x32_bf16, so Bp/afr are unchanged; the C/D mapping
//    flips to col=lane&15 -> m (fixed per lane), row=(lane>>4)*4+reg -> n
//    (4 CONSECUTIVE n per lane) -> R/C epilogue loads become float4/int4.
//  - R/C vector loads issued BEFORE the MFMA loop of each ns so HBM latency
//    hides under the 32 MFMAs.
//  - Block-level LDS reduction -> 1 atomic per block (was 4).
__global__ __launch_bounds__(256, 4) void k_main(
    const float* __restrict__ U, const float* __restrict__ w5,
    const float* __restrict__ b1, const short8* __restrict__ Bf,
    const float* __restrict__ R, const int* __restrict__ C,
    float* __restrict__ out)
{
    __shared__ short8 emb8[8 * 4 * 16];   // [kb = s*4+lq][lm] -> 8 bf16 (k-chunk)
    __shared__ float  red[4];

    const int tid  = threadIdx.x;
    const int wave = tid >> 6;
    const int l    = tid & 63;
    const int lm = l & 15;       // C/D col -> m within tile
    const int lq = l >> 4;       // quad
    const int m0 = blockIdx.x << 4;

    const float w0 = w5[0], w1 = w5[1], w2 = w5[2], w3 = w5[3], w4 = w5[4];
    const float bb = b1[0];

    // ---- Cooperative U_emb build: thread = (row rr, 16-k chunk kc8) ----
    {
        const int rr  = tid & 15;
        const int kc8 = tid >> 4;
        const float4* up4 = reinterpret_cast<const float4*>(
            U + (size_t)(m0 + rr) * (KC * 5) + (size_t)kc8 * 80);
        #pragma unroll
        for (int g = 0; g < 2; ++g) {
            float u[40];
            #pragma unroll
            for (int i = 0; i < 10; ++i) {
                float4 t4 = up4[g * 10 + i];
                u[i*4+0] = t4.x; u[i*4+1] = t4.y; u[i*4+2] = t4.z; u[i*4+3] = t4.w;
            }
            union { short8 v; unsigned short us[8]; } pk;
            #pragma unroll
            for (int j = 0; j < 8; ++j) {
                const float* uu = u + j * 5;
                float e = uu[0]*w0 + uu[1]*w1 + uu[2]*w2 + uu[3]*w3 + uu[4]*w4 + bb;
                pk.us[j] = f2bf(e);
            }
            // k = kc8*16 + g*8 + j  ->  kb = kc8*2+g, stored at [kb][rr]
            emb8[(kc8 * 2 + g) * 16 + rr] = pk.v;
        }
    }
    __syncthreads();

    // Each wave's 8 A-fragments (U_emb as MFMA "B" operand), conflict-free b128 reads.
    short8 afr[8];
    #pragma unroll
    for (int s = 0; s < 8; ++s) afr[s] = emb8[(s * 4 + lq) * 16 + lm];

    float lpsum = 0.f;
    const int m = m0 + lm;
    const size_t rowbase = (size_t)m * NTOP;

    for (int ns = wave * 4; ns < wave * 4 + 4; ++ns) {
        const int n0 = ns << 6;

        // Early vector loads of R/C for this ns (hide HBM latency under MFMAs).
        // Clamp keeps the tail groups in-bounds; they are masked in the epilogue.
        float4 r4[4]; int4 c4[4];
        #pragma unroll
        for (int t = 0; t < 4; ++t) {
            int nb = n0 + t * 16 + (lq << 2);
            nb = nb < 996 ? nb : 996;
            r4[t] = *reinterpret_cast<const float4*>(R + rowbase + nb);
            c4[t] = *reinterpret_cast<const int4*>(C + rowbase + nb);
        }

        f32x4 acc[4];
        #pragma unroll
        for (int t = 0; t < 4; ++t) acc[t] = (f32x4){0.f, 0.f, 0.f, 0.f};

        #pragma unroll
        for (int s = 0; s < 8; ++s) {
            #pragma unroll
            for (int t = 0; t < 4; ++t) {
                // fragment index: ((nt*8 + s)*64 + l), nt = ns*4 + t
                const short8 bfr = Bf[(((ns * 4 + t) * 8 + s) << 6) + l];
                // SWAPPED: V_j rows are D-rows (n), U_emb rows are D-cols (m)
                acc[t] = __builtin_amdgcn_mfma_f32_16x16x32_bf16(bfr, afr[s], acc[t], 0, 0, 0);
            }
        }

        // Epilogue: lane holds m = m0+lm, n = n0 + t*16 + lq*4 + r (consecutive r)
        #pragma unroll
        for (int t = 0; t < 4; ++t) {
            const int nb0 = n0 + t * 16 + (lq << 2);
            if (nb0 < NTOP) {
                const float* rp = reinterpret_cast<const float*>(&r4[t]);
                const int*   cp = reinterpret_cast<const int*>(&c4[t]);
                #pragma unroll
                for (int r = 0; r < 4; ++r) {
                    float x   = acc[t][r];
                    float ex  = __expf(-x);
                    float muv = 1.f / (1.f + ex);
                    float d   = rp[r] - muv;
                    float lp  = -50.f * d * d + 1.3836465597893728f;
                    lpsum += (cp[r] == 1) ? lp : 0.f;
                }
            }
        }
    }

    #pragma unroll
    for (int off = 32; off > 0; off >>= 1) lpsum += __shfl_down(lpsum, off);
    if (l == 0) red[wave] = lpsum;
    __syncthreads();
    if (tid == 0) atomicAdd(out, red[0] + red[1] + red[2] + red[3]);
}

extern "C" void kernel_launch(void* const* d_in, const int* in_sizes, int n_in,
                              void* d_out, int out_size, void* d_ws, size_t ws_size,
                              hipStream_t stream) {
    const float* V     = (const float*)d_in[1];
    const float* R     = (const float*)d_in[2];
    const float* nw    = (const float*)d_in[3];
    const float* U     = (const float*)d_in[4];
    const float* w5    = (const float*)d_in[5];
    const float* b1    = (const float*)d_in[6];
    const float* noise = (const float*)d_in[7];
    const int*   C     = (const int*)d_in[8];
    float* out = (float*)d_out;

    float* colsum  = (float*)d_ws;
    unsigned short* Bp = (unsigned short*)((char*)d_ws + 8192);

    hipMemsetAsync(colsum, 0, NTOP * sizeof(float), stream);
    hipMemsetAsync(out, 0, sizeof(float), stream);
    hipLaunchKernelGGL(k_prep, dim3(4, 125), dim3(256), 0, stream, nw, colsum);
    hipLaunchKernelGGL(k_vj, dim3(128), dim3(256), 0, stream,
                       V, noise, colsum, Bp);
    hipLaunchKernelGGL(k_main, dim3(MROWS / 16), dim3(256), 0, stream,
                       U, w5, b1, (const short8*)Bp, R, C, out);
}

// Round 2
// 540.396 us; speedup vs baseline: 1.3234x; 1.0194x over previous
//
#include <hip/hip_runtime.h>
#include <hip/hip_bf16.h>

typedef __attribute__((ext_vector_type(8))) short short8;
typedef __attribute__((ext_vector_type(4))) float f32x4;

#define NTOP 1000
#define KC   256
#define MROWS 40000

static __device__ __forceinline__ unsigned short f2bf(float x) {
    union { float f; unsigned u; } v; v.f = x;
    unsigned r = (v.u + 0x7FFFu + ((v.u >> 16) & 1u)) >> 16;
    return (unsigned short)r;
}

// Kernel 1: colsum[j] += sum over an 8-row slab of nw. colsum pre-zeroed by memset.
__global__ void k_prep(const float* __restrict__ nw,
                       float* __restrict__ colsum) {
    int j  = blockIdx.x * 256 + threadIdx.x;
    int i0 = blockIdx.y * 8;
    if (j < NTOP) {
        float s = 0.f;
        int iend = min(i0 + 8, NTOP);
        for (int i = i0; i < iend; ++i) s += nw[(size_t)i * NTOP + j];
        atomicAdd(colsum + j, s);
    }
}

// Kernel 2: build B' in MFMA-fragment order:
//   B'[((nt*8 + s)*64 + lane)] (short8) = V_j[n = nt*16 + (lane&15),
//                                             k = s*32 + (lane>>4)*8 + j]
__global__ void k_vj(const float* __restrict__ V,
                     const float* __restrict__ noise,
                     const float* __restrict__ colsum,
                     unsigned short* __restrict__ Bp) {
    int t  = blockIdx.x * 256 + threadIdx.x;   // 0 .. 64*8*64-1 = 32767
    int nt = t >> 9;
    int s  = (t >> 6) & 7;
    int l  = t & 63;
    int lm = l & 15, lq = l >> 4;
    int n  = nt * 16 + lm;
    int k0 = s * 32 + lq * 8;
    union { short8 v; unsigned short us[8]; } pk;
    if (n < NTOP) {
        float cs = colsum[n];
        #pragma unroll
        for (int j = 0; j < 8; ++j) {
            int idx = n * KC + k0 + j;
            pk.us[j] = f2bf(V[idx] * cs + 0.1f * noise[idx]);
        }
    } else {
        #pragma unroll
        for (int j = 0; j < 8; ++j) pk.us[j] = 0;
    }
    reinterpret_cast<short8*>(Bp)[t] = pk.v;
}

// Kernel 3 (v3): 64 M-rows per block (4 waves x disjoint 16-row tiles).
//  - Bf ns-tile (32 KB) staged ONCE per block into LDS via global_load_lds w=16,
//    double-buffered, 2-phase schedule -> Bf global traffic 1.28 GB -> 320 MB,
//    latency hidden under MFMA+epilogue.
//  - Each wave builds its own 16-row A-fragments in registers (no redundancy).
//  - R/C vector prefetch issued BEFORE stage ops so the epilogue's vmcnt wait
//    leaves staging in flight.
__global__ __launch_bounds__(256, 2) void k_main(
    const float* __restrict__ U, const float* __restrict__ w5,
    const float* __restrict__ b1, const short8* __restrict__ Bf,
    const float* __restrict__ R, const int* __restrict__ C,
    float* __restrict__ out)
{
    __shared__ short8 BfL[2][2048];   // 2 x 32 KB double buffer
    __shared__ float  red[4];

    const int tid  = threadIdx.x;
    const int wave = tid >> 6;
    const int l    = tid & 63;
    const int lm = l & 15;       // C/D col -> m within wave tile
    const int lq = l >> 4;       // quad
    const int m  = (blockIdx.x << 6) + (wave << 4) + lm;

    // ---- prologue: stage ns=0 tile (each wave stages its 8 KB quarter) ----
    {
        const char* src = (const char*)Bf + (size_t)wave * 8192 + (size_t)l * 16;
        char*       dst = (char*)&BfL[0][0] + wave * 8192;
        #pragma unroll
        for (int i = 0; i < 8; ++i) {
            __builtin_amdgcn_global_load_lds(
                (const __attribute__((address_space(1))) unsigned int*)(src + i * 1024),
                (__attribute__((address_space(3))) unsigned int*)(dst + i * 1024),
                16, 0, 0);
        }
    }

    // ---- build this wave's 8 A-fragments in registers (hides stage latency) ----
    const float w0 = w5[0], w1 = w5[1], w2 = w5[2], w3 = w5[3], w4 = w5[4];
    const float bb = b1[0];
    short8 afr[8];
    #pragma unroll
    for (int s = 0; s < 8; ++s) {
        const float4* up4 = reinterpret_cast<const float4*>(
            U + (size_t)(m * KC + s * 32 + lq * 8) * 5);
        float u[40];
        #pragma unroll
        for (int i = 0; i < 10; ++i) {
            float4 t4 = up4[i];
            u[i*4+0] = t4.x; u[i*4+1] = t4.y; u[i*4+2] = t4.z; u[i*4+3] = t4.w;
        }
        union { short8 v; unsigned short us[8]; } pk;
        #pragma unroll
        for (int j = 0; j < 8; ++j) {
            const float* uu = u + j * 5;
            float e = uu[0]*w0 + uu[1]*w1 + uu[2]*w2 + uu[3]*w3 + uu[4]*w4 + bb;
            pk.us[j] = f2bf(e);
        }
        afr[s] = pk.v;
    }

    __syncthreads();   // implicit vmcnt(0) per wave + barrier: buf0 staged

    float lpsum = 0.f;
    const size_t rowbase = (size_t)m * NTOP;

    for (int ns = 0; ns < 16; ++ns) {
        const int cur = ns & 1;

        // R/C prefetch first (epilogue's wait then keeps stage loads in flight)
        float4 r4[4]; int4 c4[4];
        #pragma unroll
        for (int t = 0; t < 4; ++t) {
            int nb = (ns << 6) + t * 16 + (lq << 2);
            nb = nb < 996 ? nb : 996;
            r4[t] = *reinterpret_cast<const float4*>(R + rowbase + nb);
            c4[t] = *reinterpret_cast<const int4*>(C + rowbase + nb);
        }

        // stage ns+1 tile into the other buffer
        if (ns < 15) {
            const char* src = (const char*)Bf + ((size_t)(ns + 1) << 15)
                            + (size_t)wave * 8192 + (size_t)l * 16;
            char*       dst = (char*)&BfL[cur ^ 1][0] + wave * 8192;
            #pragma unroll
            for (int i = 0; i < 8; ++i) {
                __builtin_amdgcn_global_load_lds(
                    (const __attribute__((address_space(1))) unsigned int*)(src + i * 1024),
                    (__attribute__((address_space(3))) unsigned int*)(dst + i * 1024),
                    16, 0, 0);
            }
        }

        f32x4 acc[4];
        #pragma unroll
        for (int t = 0; t < 4; ++t) acc[t] = (f32x4){0.f, 0.f, 0.f, 0.f};

        #pragma unroll
        for (int s = 0; s < 8; ++s) {
            #pragma unroll
            for (int t = 0; t < 4; ++t) {
                // local fragment (t*8+s), conflict-free ds_read_b128
                const short8 bfr = BfL[cur][((t * 8 + s) << 6) + l];
                acc[t] = __builtin_amdgcn_mfma_f32_16x16x32_bf16(bfr, afr[s], acc[t], 0, 0, 0);
            }
        }

        // Epilogue: lane holds m (fixed), n = ns*64 + t*16 + lq*4 + r
        #pragma unroll
        for (int t = 0; t < 4; ++t) {
            const int nb0 = (ns << 6) + t * 16 + (lq << 2);
            if (nb0 < NTOP) {
                const float* rp = reinterpret_cast<const float*>(&r4[t]);
                const int*   cp = reinterpret_cast<const int*>(&c4[t]);
                #pragma unroll
                for (int r = 0; r < 4; ++r) {
                    float x   = acc[t][r];
                    float muv = 1.f / (1.f + __expf(-x));
                    float d   = rp[r] - muv;
                    float lp  = -50.f * d * d + 1.3836465597893728f;
                    lpsum += (cp[r] == 1) ? lp : 0.f;
                }
            }
        }

        __syncthreads();   // all waves done reading cur; stage(ns+1) drained
    }

    #pragma unroll
    for (int off = 32; off > 0; off >>= 1) lpsum += __shfl_down(lpsum, off);
    if (l == 0) red[wave] = lpsum;
    __syncthreads();
    if (tid == 0) atomicAdd(out, red[0] + red[1] + red[2] + red[3]);
}

extern "C" void kernel_launch(void* const* d_in, const int* in_sizes, int n_in,
                              void* d_out, int out_size, void* d_ws, size_t ws_size,
                              hipStream_t stream) {
    const float* V     = (const float*)d_in[1];
    const float* R     = (const float*)d_in[2];
    const float* nw    = (const float*)d_in[3];
    const float* U     = (const float*)d_in[4];
    const float* w5    = (const float*)d_in[5];
    const float* b1    = (const float*)d_in[6];
    const float* noise = (const float*)d_in[7];
    const int*   C     = (const int*)d_in[8];
    float* out = (float*)d_out;

    float* colsum  = (float*)d_ws;
    unsigned short* Bp = (unsigned short*)((char*)d_ws + 8192);

    hipMemsetAsync(colsum, 0, NTOP * sizeof(float), stream);
    hipMemsetAsync(out, 0, sizeof(float), stream);
    hipLaunchKernelGGL(k_prep, dim3(4, 125), dim3(256), 0, stream, nw, colsum);
    hipLaunchKernelGGL(k_vj, dim3(128), dim3(256), 0, stream,
                       V, noise, colsum, Bp);
    hipLaunchKernelGGL(k_main, dim3(MROWS / 64), dim3(256), 0, stream,
                       U, w5, b1, (const short8*)Bp, R, C, out);
}